// Round 5
// baseline (471.102 us; speedup 1.0000x reference)
//
#include <hip/hip_runtime.h>

typedef __bf16 bf16x8 __attribute__((ext_vector_type(8)));
typedef _Float16 f16x8 __attribute__((ext_vector_type(8)));
typedef float floatx4 __attribute__((ext_vector_type(4)));

__device__ __forceinline__ unsigned short f2bf(float f) {
  unsigned int u = __float_as_uint(f);
  u += 0x7FFFu + ((u >> 16) & 1u);  // RNE
  return (unsigned short)(u >> 16);
}
__device__ __forceinline__ unsigned short f2h(float f) {
  _Float16 h = (_Float16)f;
  return __builtin_bit_cast(unsigned short, h);
}
template <bool F16>
__device__ __forceinline__ unsigned short f2x(float f) {
  return F16 ? f2h(f) : f2bf(f);
}

// async global->LDS, 16B per lane. LDS dest = wave-uniform base + lane*16.
__device__ __forceinline__ void g2l16(const void* g, void* l) {
  __builtin_amdgcn_global_load_lds(
      (const __attribute__((address_space(1))) void*)g,
      (__attribute__((address_space(3))) void*)l, 16, 0, 0);
}

template <bool F16> struct ABsel { using t = bf16x8; };
template <> struct ABsel<true> { using t = f16x8; };
__device__ __forceinline__ floatx4 mfma_ab(f16x8 b, f16x8 a, floatx4 c) {
  return __builtin_amdgcn_mfma_f32_16x16x32_f16(b, a, c, 0, 0, 0);
}
__device__ __forceinline__ floatx4 mfma_ab(bf16x8 b, bf16x8 a, floatx4 c) {
  return __builtin_amdgcn_mfma_f32_16x16x32_bf16(b, a, c, 0, 0, 0);
}

// ===========================================================================
// gemm256: C[M,N] = A[M,K]*B[N,K]^T, 256x256x64 tile, 8 waves (512 thr),
// 128 KiB double-buffered LDS, 8-phase counted-vmcnt schedule (T3+T4+T5+T2+T1).
//
// Round-4 diagnosis: 128^2 2-phase structure is LDS-BW + barrier-drain bound
// (per-wave FLOP/LDS-byte = 32; model predicts 30% MfmaUtil, measured 29%).
// This is the guide's m201 geometry: per-wave output 128x64 (8x4 16x16 frags),
// per K-tile 4 phases, each phase = {stage 1 chunk of tile t+1 || ds_read one
// register quadrant of tile t -> vmcnt(6) gate + s_barrier -> setprio(1) +
// 16 MFMA + setprio(0) -> s_barrier}.
//
// Chunk order == consumption order (so every steady gate is vmcnt(6)):
//   C0 = A rows {0-63,128-191}   (phase-0 A-quad rows of both wave-rows)
//   C1 = B rows {0-31,64-95,128-159,192-223}   (phase-0 B-quads)
//   C2 = B rows {32-63,96-127,160-191,224-255} (phase-1 B-quads)
//   C3 = A rows {64-127,192-255}               (phase-2 A-quads)
// Ledger (steady state, 2 loads/chunk/thread): at each gate the newest 3
// chunks may be in flight; the chunk being ds_read this phase has landed.
// Tail tile (no prefetch) drains vmcnt 4 -> 2 -> 0.
//
// LDS XOR swizzle as proven in r3/r4 (conflicts 2.5e7 -> 0): 16B slot s of
// row r holds global slot s^(r&7); g2l16 dest stays linear, global source is
// pre-swizzled, ds_read applies the same XOR (rule #21).
// MFMA operands SWAPPED (mfma(b,a)): lane (qr,lr), frag (mi,nj), reg r holds
//   C[m0+wr+mi*16+lr][n0+wc+nj*16+qr*4+r]  -> vectorized epilogue stores.
// MODE 0: C = relu(acc+bias[col]) -> fp16 if OUTF16 else bf16
// MODE 1: C = exp(acc-60) -> bf16, lrow[z*2048+row] += rowsum (atomics)
// MODE 2: C = acc / lrow[z*2048+row] -> fp32
// ===========================================================================

#define STAGE(C, TT, BD)                                                       \
  {                                                                            \
    const int k0s = (TT) << 6;                                                 \
    _Pragma("unroll") for (int it = 0; it < 2; ++it) {                         \
      const int cr0 = it * 64 + wave * 8; /* wave-uniform group base row */    \
      int rb;                                                                  \
      if ((C) == 0)                                                            \
        rb = (cr0 < 64) ? cr0 : cr0 + 64;                                      \
      else if ((C) == 3)                                                       \
        rb = ((cr0 < 64) ? cr0 : cr0 + 64) + 64;                               \
      else if ((C) == 1)                                                       \
        rb = (cr0 & 31) + (cr0 >> 5) * 64;                                     \
      else                                                                     \
        rb = (cr0 & 31) + (cr0 >> 5) * 64 + 32;                                \
      const int rl = rb + (lane >> 3);      /* per-lane row (rb%8==0) */       \
      const int gs = (lane & 7) ^ (lane >> 3); /* inverse-swizzled slot */     \
      if ((C) == 0 || (C) == 3)                                                \
        g2l16(A + (size_t)(m0 + rl) * lda + k0s + gs * 8, &As[BD][rb * 64]);   \
      else                                                                     \
        g2l16(B + (size_t)(n0 + rl) * ldb + k0s + gs * 8, &Bs[BD][rb * 64]);   \
    }                                                                          \
  }

#define LOADA(MH, BD)                                                          \
  _Pragma("unroll") for (int i = 0; i < 4; ++i) {                              \
    const int ra = wr + (MH) * 64 + i * 16 + lr;                               \
    _Pragma("unroll") for (int ks = 0; ks < 2; ++ks) {                         \
      const int sl = ks * 4 + qr;                                              \
      af[i][ks] = *(const AB8*)&As[BD][ra * 64 + ((sl ^ (ra & 7)) * 8)];       \
    }                                                                          \
  }

#define LOADB(DST, NH, BD)                                                     \
  _Pragma("unroll") for (int j = 0; j < 2; ++j) {                              \
    const int rq = wc + (NH) * 32 + j * 16 + lr;                               \
    _Pragma("unroll") for (int ks = 0; ks < 2; ++ks) {                         \
      const int sl = ks * 4 + qr;                                              \
      DST[j][ks] = *(const AB8*)&Bs[BD][rq * 64 + ((sl ^ (rq & 7)) * 8)];      \
    }                                                                          \
  }

#define MMAQ(MH, NH, BF)                                                       \
  __builtin_amdgcn_s_setprio(1);                                               \
  _Pragma("unroll") for (int ks = 0; ks < 2; ++ks)                             \
      _Pragma("unroll") for (int i = 0; i < 4; ++i)                            \
          _Pragma("unroll") for (int j = 0; j < 2; ++j)                        \
              acc[(MH) * 4 + i][(NH) * 2 + j] = mfma_ab(                       \
                  BF[j][ks], af[i][ks], acc[(MH) * 4 + i][(NH) * 2 + j]);      \
  __builtin_amdgcn_s_setprio(0);

#define GATE(N)                                                                \
  __builtin_amdgcn_sched_barrier(0);                                           \
  asm volatile("s_waitcnt vmcnt(" #N ")" ::: "memory");                        \
  __builtin_amdgcn_s_barrier();                                                \
  __builtin_amdgcn_sched_barrier(0);

#define PHEND                                                                  \
  __builtin_amdgcn_sched_barrier(0);                                           \
  __builtin_amdgcn_s_barrier();                                                \
  __builtin_amdgcn_sched_barrier(0);

template <int MODE, bool INF16, bool OUTF16>
__global__ __launch_bounds__(512, 2) void gemm256(
    const unsigned short* __restrict__ A, int lda, long sA,
    const unsigned short* __restrict__ B, int ldb, long sB,
    void* __restrict__ Cv, int ldc, long sC,
    int K, const float* __restrict__ bias, float* __restrict__ lrow) {
  __shared__ unsigned short As[2][256 * 64];
  __shared__ unsigned short Bs[2][256 * 64];
  const int tid = threadIdx.x;
  const int wave = tid >> 6, lane = tid & 63;
  const int z = blockIdx.z;
  A += (size_t)z * sA;
  B += (size_t)z * sB;

  // T1: XCD-aware bijective chunking of the (x,y) plane (all grids %8==0).
  int bx = blockIdx.x, by = blockIdx.y;
  {
    const int nwg = gridDim.x * gridDim.y;
    if ((nwg & 7) == 0) {
      int flat = by * gridDim.x + bx;
      flat = (flat & 7) * (nwg >> 3) + (flat >> 3);
      bx = flat % gridDim.x;
      by = flat / gridDim.x;
    }
  }
  const int m0 = by * 256, n0 = bx * 256;
  const int wr = (wave >> 2) * 128;  // wave-row: 2 x 128
  const int wc = (wave & 3) * 64;    // wave-col: 4 x 64
  const int qr = lane >> 4, lr = lane & 15;
  using AB8 = typename ABsel<INF16>::t;
  floatx4 acc[8][4] = {};
  AB8 af[4][2], b0[2][2], b1[2][2];

  const int nt = K >> 6;
  // prologue: stage tile 0 in consumption order
  STAGE(0, 0, 0) STAGE(1, 0, 0) STAGE(2, 0, 0) STAGE(3, 0, 0)

  for (int t = 0; t < nt - 1; ++t) {
    const int d = t & 1, e = d ^ 1;
    // ph0: Q00 = A-quad0 x B-quad0
    STAGE(0, t + 1, e)
    GATE(6)
    LOADA(0, d) LOADB(b0, 0, d)
    MMAQ(0, 0, b0)
    PHEND
    // ph1: Q01 = A-quad0 x B-quad1
    STAGE(1, t + 1, e)
    GATE(6)
    LOADB(b1, 1, d)
    MMAQ(0, 1, b1)
    PHEND
    // ph2: Q11 = A-quad1 x B-quad1
    STAGE(2, t + 1, e)
    GATE(6)
    LOADA(1, d)
    MMAQ(1, 1, b1)
    PHEND
    // ph3: Q10 = A-quad1 x B-quad0 (regs only)
    STAGE(3, t + 1, e)
    __builtin_amdgcn_sched_barrier(0);
    MMAQ(1, 0, b0)
    PHEND
  }
  {  // tail tile: no prefetch; drain 4 -> 2 -> 0
    const int t = nt - 1, d = t & 1;
    GATE(4)
    LOADA(0, d) LOADB(b0, 0, d)
    MMAQ(0, 0, b0)
    PHEND
    GATE(2)
    LOADB(b1, 1, d)
    MMAQ(0, 1, b1)
    PHEND
    GATE(0)
    LOADA(1, d)
    MMAQ(1, 1, b1)
    PHEND
    MMAQ(1, 0, b0)
  }

  // Epilogue: row = m0+wr+mi*16+lr ; col = n0+wc+nj*16+qr*4+r
  float* Cf = (float*)Cv + (size_t)z * sC;
  unsigned short* Cb = (unsigned short*)Cv + (size_t)z * sC;
#pragma unroll
  for (int mi = 0; mi < 8; ++mi) {
    const int row = m0 + wr + mi * 16 + lr;
    float rowsum = 0.0f;
    float invl = 1.0f;
    if (MODE == 2) invl = 1.0f / lrow[(size_t)z * 2048 + row];
#pragma unroll
    for (int nj = 0; nj < 4; ++nj) {
      const int col0 = n0 + wc + nj * 16 + qr * 4;
      if (MODE == 0) {
        float4 bj = *(const float4*)(bias + col0);
        float v0 = fmaxf(acc[mi][nj][0] + bj.x, 0.0f);
        float v1 = fmaxf(acc[mi][nj][1] + bj.y, 0.0f);
        float v2 = fmaxf(acc[mi][nj][2] + bj.z, 0.0f);
        float v3 = fmaxf(acc[mi][nj][3] + bj.w, 0.0f);
        *(ushort4*)&Cb[(size_t)row * ldc + col0] =
            make_ushort4(f2x<OUTF16>(v0), f2x<OUTF16>(v1), f2x<OUTF16>(v2),
                         f2x<OUTF16>(v3));
      } else if (MODE == 1) {
        float e0 = __expf(acc[mi][nj][0] - 60.0f);
        float e1 = __expf(acc[mi][nj][1] - 60.0f);
        float e2 = __expf(acc[mi][nj][2] - 60.0f);
        float e3 = __expf(acc[mi][nj][3] - 60.0f);
        *(ushort4*)&Cb[(size_t)row * ldc + col0] =
            make_ushort4(f2bf(e0), f2bf(e1), f2bf(e2), f2bf(e3));
        rowsum += (e0 + e1) + (e2 + e3);
      } else {
        *(float4*)&Cf[(size_t)row * ldc + col0] =
            make_float4(acc[mi][nj][0] * invl, acc[mi][nj][1] * invl,
                        acc[mi][nj][2] * invl, acc[mi][nj][3] * invl);
      }
    }
    if (MODE == 1) {
      rowsum += __shfl_xor(rowsum, 16);
      rowsum += __shfl_xor(rowsum, 32);
      if (lane < 16) atomicAdd(&lrow[(size_t)z * 2048 + row], rowsum);
    }
  }
}

// ===========================================================================
// Legacy 128^2 kernel (round-4, verified): kept ONLY for the AF32 V-proj in
// the SMALL path (fp32 A staged via ds_write; incompatible with the vmcnt
// ledger of gemm256).
// ===========================================================================
template <int MODE, bool AF32, bool INF16, bool OUTF16>
__global__ __launch_bounds__(256) void gemm_bt(
    const void* __restrict__ Av, int lda, long sA,
    const unsigned short* __restrict__ B, int ldb, long sB,
    void* __restrict__ Cv, int ldc, long sC,
    int K, const float* __restrict__ bias, float* __restrict__ lrow) {
  __shared__ unsigned short Asl[128 * 64];
  __shared__ unsigned short Bsl[128 * 64];
  const int tid = threadIdx.x;
  const int wave = tid >> 6, lane = tid & 63;
  const int z = blockIdx.z;
  const float* A32 = (const float*)Av + (size_t)z * sA;
  B += (size_t)z * sB;
  int bx = blockIdx.x, by = blockIdx.y;
  {
    const int nwg = gridDim.x * gridDim.y;
    if ((nwg & 7) == 0) {
      int flat = by * gridDim.x + bx;
      flat = (flat & 7) * (nwg >> 3) + (flat >> 3);
      bx = flat % gridDim.x;
      by = flat / gridDim.x;
    }
  }
  const int m0 = by * 128, n0 = bx * 128;
  const int wr = (wave >> 1) * 64;
  const int wc = (wave & 1) * 64;
  const int qr = lane >> 4, lr = lane & 15;
  floatx4 acc[4][4] = {};

  for (int k0 = 0; k0 < K; k0 += 64) {
    __syncthreads();
#pragma unroll
    for (int it = 0; it < 8; ++it) {
      const int idx = it * 256 + tid;
      const int row = idx >> 4, c4 = idx & 15;
      float4 v = *(const float4*)(A32 + (size_t)(m0 + row) * lda + k0 + c4 * 4);
      const int soff = (((c4 >> 1) ^ (row & 7)) * 2 + (c4 & 1)) * 4;
      *(ushort4*)&Asl[row * 64 + soff] =
          make_ushort4(f2x<INF16>(v.x), f2x<INF16>(v.y), f2x<INF16>(v.z),
                       f2x<INF16>(v.w));
    }
#pragma unroll
    for (int it = 0; it < 4; ++it) {
      const int base = it * 256 + wave * 64;
      const int idx = base + lane;
      const int row = idx >> 3;
      const int gs = (idx & 7) ^ (row & 7);
      g2l16(B + (size_t)(n0 + row) * ldb + k0 + gs * 8, &Bsl[base * 8]);
    }
    __syncthreads();
#pragma unroll
    for (int kk = 0; kk < 64; kk += 32) {
      const int slot = (kk >> 3) + qr;
      bf16x8 af[4], bf[4];
#pragma unroll
      for (int i = 0; i < 4; ++i) {
        const int ra = wr + i * 16 + lr;
        af[i] = *(const bf16x8*)&Asl[ra * 64 + ((slot ^ (ra & 7)) * 8)];
      }
#pragma unroll
      for (int j = 0; j < 4; ++j) {
        const int rb = wc + j * 16 + lr;
        bf[j] = *(const bf16x8*)&Bsl[rb * 64 + ((slot ^ (rb & 7)) * 8)];
      }
#pragma unroll
      for (int i = 0; i < 4; ++i)
#pragma unroll
        for (int j = 0; j < 4; ++j)
          acc[i][j] = __builtin_amdgcn_mfma_f32_16x16x32_bf16(bf[j], af[i],
                                                              acc[i][j], 0, 0, 0);
    }
  }

  float* Cf = (float*)Cv + (size_t)z * sC;
  unsigned short* Cb = (unsigned short*)Cv + (size_t)z * sC;
#pragma unroll
  for (int i = 0; i < 4; ++i) {
    const int row = m0 + wr + i * 16 + lr;
    float rowsum = 0.0f;
    float invl = 1.0f;
    if (MODE == 2) invl = 1.0f / lrow[(size_t)z * 2048 + row];
#pragma unroll
    for (int j = 0; j < 4; ++j) {
      const int col0 = n0 + wc + j * 16 + qr * 4;
      if (MODE == 0) {
        float4 bj = *(const float4*)(bias + col0);
        float v0 = fmaxf(acc[i][j][0] + bj.x, 0.0f);
        float v1 = fmaxf(acc[i][j][1] + bj.y, 0.0f);
        float v2 = fmaxf(acc[i][j][2] + bj.z, 0.0f);
        float v3 = fmaxf(acc[i][j][3] + bj.w, 0.0f);
        *(ushort4*)&Cb[(size_t)row * ldc + col0] =
            make_ushort4(f2x<OUTF16>(v0), f2x<OUTF16>(v1), f2x<OUTF16>(v2),
                         f2x<OUTF16>(v3));
      } else if (MODE == 1) {
        float e0 = __expf(acc[i][j][0] - 60.0f);
        float e1 = __expf(acc[i][j][1] - 60.0f);
        float e2 = __expf(acc[i][j][2] - 60.0f);
        float e3 = __expf(acc[i][j][3] - 60.0f);
        *(ushort4*)&Cb[(size_t)row * ldc + col0] =
            make_ushort4(f2bf(e0), f2bf(e1), f2bf(e2), f2bf(e3));
        rowsum += (e0 + e1) + (e2 + e3);
      } else {
        *(float4*)&Cf[(size_t)row * ldc + col0] =
            make_float4(acc[i][j][0] * invl, acc[i][j][1] * invl,
                        acc[i][j][2] * invl, acc[i][j][3] * invl);
      }
    }
    if (MODE == 1) {
      rowsum += __shfl_xor(rowsum, 16);
      rowsum += __shfl_xor(rowsum, 32);
      if (lane < 16) atomicAdd(&lrow[(size_t)z * 2048 + row], rowsum);
    }
  }
}

// fp32 -> fp16/bf16 elementwise
template <bool F16>
__global__ __launch_bounds__(256) void cvt16(const float* __restrict__ in,
                                             unsigned short* __restrict__ out,
                                             int n) {
  const int i = (blockIdx.x * 256 + threadIdx.x) * 8;
  if (i >= n) return;
  float4 a = *(const float4*)(in + i);
  float4 b = *(const float4*)(in + i + 4);
  *(ushort4*)(out + i) =
      make_ushort4(f2x<F16>(a.x), f2x<F16>(a.y), f2x<F16>(a.z), f2x<F16>(a.w));
  *(ushort4*)(out + i + 4) =
      make_ushort4(f2x<F16>(b.x), f2x<F16>(b.y), f2x<F16>(b.z), f2x<F16>(b.w));
}

// W[1024][1024] fp32 -> Wt[1024][1024] fp16/bf16 transposed
template <bool F16>
__global__ __launch_bounds__(256) void wtrans(const float* __restrict__ W,
                                              unsigned short* __restrict__ Wt) {
  __shared__ unsigned short t[64][68];
  const int tid = threadIdx.x;
  const int n0 = blockIdx.x * 64, k0 = blockIdx.y * 64;
#pragma unroll
  for (int it = 0; it < 4; ++it) {
    const int idx = it * 256 + tid;
    const int kr = idx >> 4, nq = idx & 15;
    float4 v = *(const float4*)&W[(size_t)(k0 + kr) * 1024 + n0 + nq * 4];
    t[kr][nq * 4 + 0] = f2x<F16>(v.x);
    t[kr][nq * 4 + 1] = f2x<F16>(v.y);
    t[kr][nq * 4 + 2] = f2x<F16>(v.z);
    t[kr][nq * 4 + 3] = f2x<F16>(v.w);
  }
  __syncthreads();
#pragma unroll
  for (int it = 0; it < 4; ++it) {
    const int idx = it * 256 + tid;
    const int nr = idx >> 4, kq = idx & 15;
    *(ushort4*)&Wt[(size_t)(n0 + nr) * 1024 + k0 + kq * 4] =
        make_ushort4(t[kq * 4 + 0][nr], t[kq * 4 + 1][nr],
                     t[kq * 4 + 2][nr], t[kq * 4 + 3][nr]);
  }
}

// V[b][t][v] 16-bit -> Vt[b][v][t] 16-bit (dtype-agnostic)
__global__ __launch_bounds__(256) void vtrans(const unsigned short* __restrict__ V,
                                              unsigned short* __restrict__ Vt) {
  __shared__ unsigned short t[64][68];
  const int tid = threadIdx.x;
  const int v0 = blockIdx.x * 64, t0 = blockIdx.y * 64;
  const int b = blockIdx.z;
  const unsigned short* Vb = V + (size_t)b * 2048 * 1024;
  unsigned short* Vtb = Vt + (size_t)b * 1024 * 2048;
#pragma unroll
  for (int it = 0; it < 4; ++it) {
    const int idx = it * 256 + tid;
    const int tr = idx >> 4, vq = idx & 15;
    ushort4 u = *(const ushort4*)&Vb[(size_t)(t0 + tr) * 1024 + v0 + vq * 4];
    t[tr][vq * 4 + 0] = u.x;
    t[tr][vq * 4 + 1] = u.y;
    t[tr][vq * 4 + 2] = u.z;
    t[tr][vq * 4 + 3] = u.w;
  }
  __syncthreads();
#pragma unroll
  for (int it = 0; it < 4; ++it) {
    const int idx = it * 256 + tid;
    const int vr = idx >> 4, tq = idx & 15;
    *(ushort4*)&Vtb[(size_t)(v0 + vr) * 2048 + t0 + tq * 4] =
        make_ushort4(t[tq * 4 + 0][vr], t[tq * 4 + 1][vr],
                     t[tq * 4 + 2][vr], t[tq * 4 + 3][vr]);
  }
}

__global__ void zero_f32(float* __restrict__ p, int n) {
  const int i = blockIdx.x * 256 + threadIdx.x;
  if (i < n) p[i] = 0.0f;
}

// Copy half-output T[b][0..1023][1024] fp32 -> out[b][roff+0..1023][1024].
__global__ __launch_bounds__(256) void copy_half(const float* __restrict__ T,
                                                 float* __restrict__ out,
                                                 int roff) {
  const size_t i = ((size_t)blockIdx.x * 256 + threadIdx.x) * 4;
  const size_t b = i >> 20;
  const size_t rem = i & 1048575;
  float4 v = *(const float4*)(T + i);
  *(float4*)(out + b * 2097152 + (size_t)roff * 1024 + rem) = v;
}

__global__ void diag_ws(float* __restrict__ out, float mb) { out[0] = mb; }

extern "C" void kernel_launch(void* const* d_in, const int* in_sizes, int n_in,
                              void* d_out, int out_size, void* d_ws, size_t ws_size,
                              hipStream_t stream) {
  const float* X = (const float*)d_in[0];
  const float* Wq = (const float*)d_in[1];
  const float* bq = (const float*)d_in[2];
  const float* Wk = (const float*)d_in[3];
  const float* bk = (const float*)d_in[4];
  const float* Wv = (const float*)d_in[5];
  const float* bv = (const float*)d_in[6];
  float* out = (float*)d_out;
  char* ws = (char*)d_ws;
  const size_t MiB = 1ull << 20;

  // ---- BIG layout (ws >= ~134 MB): E lives in ws -> no GEMM3 aliasing ----
  const size_t B_WQT = 0, B_WKT = 2 * MiB, B_WVT = 4 * MiB;
  const size_t B_Q = 6 * MiB;     // 32 MiB fp16
  const size_t B_K = 38 * MiB;    // 32 MiB fp16
  const size_t B_E = 70 * MiB;    // 64 MiB bf16
  const size_t B_L = 134 * MiB;   // 64 KiB
  const size_t NEEDED_BIG = B_L + 65536;

  // ---- SMALL layout: E overlays d_out, bounce GEMM3 ----
  const size_t S_WQT = 0, S_WKT = 2 * MiB, S_WVT = 4 * MiB;
  const size_t S_Q = 6 * MiB, S_K = 38 * MiB, S_L = 70 * MiB;
  const size_t NEEDED_SMALL = S_L + 65536;

  if (ws_size >= NEEDED_BIG) {
    unsigned short* Wqt = (unsigned short*)(ws + B_WQT);
    unsigned short* Wkt = (unsigned short*)(ws + B_WKT);
    unsigned short* Wvt = (unsigned short*)(ws + B_WVT);
    unsigned short* Q   = (unsigned short*)(ws + B_Q);
    unsigned short* Kb  = (unsigned short*)(ws + B_K);
    unsigned short* E   = (unsigned short*)(ws + B_E);
    float* l            = (float*)(ws + B_L);
    unsigned short* Xh = (unsigned short*)d_out;
    unsigned short* V  = (unsigned short*)d_out + 16384ull * 1024;

    cvt16<true><<<8192, 256, 0, stream>>>(X, Xh, 16384 * 1024);
    wtrans<true><<<dim3(16, 16), 256, 0, stream>>>(Wq, Wqt);
    wtrans<true><<<dim3(16, 16), 256, 0, stream>>>(Wk, Wkt);
    wtrans<true><<<dim3(16, 16), 256, 0, stream>>>(Wv, Wvt);
    zero_f32<<<64, 256, 0, stream>>>(l, 16384);

    // projections (fp16 in; Q,K fp16 out; V bf16 out into d_out upper half)
    gemm256<0, true, true><<<dim3(4, 64, 1), 512, 0, stream>>>(
        Xh, 1024, 0, Wqt, 1024, 0, Q, 1024, 0, 1024, bq, nullptr);
    gemm256<0, true, true><<<dim3(4, 64, 1), 512, 0, stream>>>(
        Xh, 1024, 0, Wkt, 1024, 0, Kb, 1024, 0, 1024, bk, nullptr);
    gemm256<0, true, false><<<dim3(4, 64, 1), 512, 0, stream>>>(
        Xh, 1024, 0, Wvt, 1024, 0, V, 1024, 0, 1024, bv, nullptr);

    // E[b] = exp(Q K^T - 60) bf16 into ws; l rowsums
    gemm256<1, true, false><<<dim3(8, 8, 8), 512, 0, stream>>>(
        Q, 1024, 2048L * 1024, Kb, 1024, 2048L * 1024,
        E, 2048, 2048L * 2048, 1024, nullptr, l);

    // V -> V^T into Q's space (Q dead after GEMM2)
    vtrans<<<dim3(16, 32, 8), 256, 0, stream>>>(V, Q);

    // out = (E * Vt^T)/l straight into d_out
    gemm256<2, false, false><<<dim3(4, 8, 8), 512, 0, stream>>>(
        E, 2048, 2048L * 2048, Q, 2048, 1024L * 2048,
        out, 1024, 2048L * 1024, 2048, nullptr, l);
    return;
  }

  if (ws_size < NEEDED_SMALL) {
    diag_ws<<<1, 1, 0, stream>>>(out, (float)(ws_size >> 20));
    return;
  }

  // ---------------- SMALL path ----------------
  unsigned short* Wqt = (unsigned short*)(ws + S_WQT);
  unsigned short* Wkt = (unsigned short*)(ws + S_WKT);
  unsigned short* Wvt = (unsigned short*)(ws + S_WVT);
  unsigned short* Q   = (unsigned short*)(ws + S_Q);
  unsigned short* Kb  = (unsigned short*)(ws + S_K);
  float* l            = (float*)(ws + S_L);
  unsigned short* Xh = (unsigned short*)d_out;
  unsigned short* E  = (unsigned short*)d_out;

  cvt16<true><<<8192, 256, 0, stream>>>(X, Xh, 16384 * 1024);
  wtrans<true><<<dim3(16, 16), 256, 0, stream>>>(Wq, Wqt);
  wtrans<true><<<dim3(16, 16), 256, 0, stream>>>(Wk, Wkt);
  wtrans<true><<<dim3(16, 16), 256, 0, stream>>>(Wv, Wvt);
  zero_f32<<<64, 256, 0, stream>>>(l, 16384);

  gemm256<0, true, true><<<dim3(4, 64, 1), 512, 0, stream>>>(
      Xh, 1024, 0, Wqt, 1024, 0, Q, 1024, 0, 1024, bq, nullptr);
  gemm256<0, true, true><<<dim3(4, 64, 1), 512, 0, stream>>>(
      Xh, 1024, 0, Wkt, 1024, 0, Kb, 1024, 0, 1024, bk, nullptr);

  gemm256<1, true, false><<<dim3(8, 8, 8), 512, 0, stream>>>(
      Q, 1024, 2048L * 1024, Kb, 1024, 2048L * 1024,
      E, 2048, 2048L * 2048, 1024, nullptr, l);

  // V-proj from fp32 X (E overlays Xh in d_out): legacy AF32 kernel
  gemm_bt<0, true, true, false><<<dim3(8, 128, 1), 256, 0, stream>>>(
      X, 1024, 0, Wvt, 1024, 0, Kb, 1024, 0, 1024, bv, nullptr);

  vtrans<<<dim3(16, 32, 8), 256, 0, stream>>>(Kb, Q);

  float* T = (float*)Kb;
  gemm256<2, false, false><<<dim3(4, 4, 8), 512, 0, stream>>>(
      E, 2048, 2048L * 2048, Q, 2048, 1024L * 2048,
      T, 1024, 1024L * 1024, 2048, nullptr, l);
  copy_half<<<8192, 256, 0, stream>>>(T, out, 0);
  gemm256<2, false, false><<<dim3(4, 4, 8), 512, 0, stream>>>(
      E + 1024L * 2048, 2048, 2048L * 2048, Q, 2048, 1024L * 2048,
      T, 1024, 1024L * 1024, 2048, nullptr, l + 1024);
  copy_half<<<8192, 256, 0, stream>>>(T, out, 1024);
}

// Round 6
// 440.735 us; speedup vs baseline: 1.0689x; 1.0689x over previous
//
#include <hip/hip_runtime.h>

typedef __bf16 bf16x8 __attribute__((ext_vector_type(8)));
typedef _Float16 f16x8 __attribute__((ext_vector_type(8)));
typedef float floatx4 __attribute__((ext_vector_type(4)));

__device__ __forceinline__ unsigned short f2bf(float f) {
  unsigned int u = __float_as_uint(f);
  u += 0x7FFFu + ((u >> 16) & 1u);  // RNE
  return (unsigned short)(u >> 16);
}
__device__ __forceinline__ unsigned short f2h(float f) {
  _Float16 h = (_Float16)f;
  return __builtin_bit_cast(unsigned short, h);
}
template <bool F16>
__device__ __forceinline__ unsigned short f2x(float f) {
  return F16 ? f2h(f) : f2bf(f);
}
__device__ __forceinline__ unsigned short f2rt(float f, bool f16) {
  return f16 ? f2h(f) : f2bf(f);
}

// async global->LDS, 16B per lane. LDS dest = wave-uniform base + lane*16.
__device__ __forceinline__ void g2l16(const void* g, void* l) {
  __builtin_amdgcn_global_load_lds(
      (const __attribute__((address_space(1))) void*)g,
      (__attribute__((address_space(3))) void*)l, 16, 0, 0);
}

// ---------------------------------------------------------------------------
// C[M,N] = A[M,K] * B[N,K]^T. 128x128x64 tile, 4 waves, 4x4 of 16x16x32 MFMA.
// == The round-4 verified kernel (443 us) ==  (round-5's 256^2/8-phase/1-blk-CU
// variant REGRESSED: 1 block/CU lockstep exposes memory latency; 2-4 blocks/CU
// of TLP on this structure beats schedule-ILP at these shapes.)
//  * T4 counted-vmcnt pipeline: double-buffered LDS; stage tile t+1 BEFORE
//    computing tile t; raw s_barrier; s_waitcnt vmcnt(8) keeps next-tile loads
//    in flight across the barrier.
//  * T1 XCD chunking of the (x,y) plane.
//  * T2 LDS XOR swizzle: 16B slot s of row r holds global slot s^(r&7);
//    g2l16 dest linear, global source pre-swizzled, ds_read same XOR (#21).
// MFMA operands SWAPPED (mfma(b,a)): lane (qr,lr), frag (i,j), reg r holds
//   C[m0+wr+i*16+lr][n0+wc+j*16+qr*4+r] -> vectorized epilogue.
// MODE 0: C = relu(acc + bias[col]) -> fp16 if OUTF16 else bf16
// MODE 1: C = exp(acc - 60) -> bf16, lrow[z*2048+row] += rowsum (atomics)
// MODE 2: C = acc / lrow[z*2048+row] -> fp32
// AF32:   A fp32 in global, converted during staging (legacy sync loop).
// PROJ3:  fused projections. z selects {B = Bbase + z*sB (weights contiguous
//         in ws), bias = bcat + z*1024, C = {Cv, C1, C2}[z]}; output dtype
//         fp16 for z<2 (Q,K), bf16 for z==2 (V). sA = sC = 0.
// ---------------------------------------------------------------------------
template <int MODE, bool AF32, bool INF16, bool OUTF16, bool PROJ3>
__global__ __launch_bounds__(256) void gemm_bt(
    const void* __restrict__ Av, int lda, long sA,
    const unsigned short* __restrict__ B, int ldb, long sB,
    void* __restrict__ Cv, int ldc, long sC,
    int K, const float* __restrict__ bias, float* __restrict__ lrow,
    void* __restrict__ C1, void* __restrict__ C2) {
  __shared__ unsigned short As[2][128 * 64];
  __shared__ unsigned short Bs[2][128 * 64];
  const int tid = threadIdx.x;
  const int wave = tid >> 6, lane = tid & 63;
  const int z = blockIdx.z;
  const unsigned short* A16 = (const unsigned short*)Av + (size_t)z * sA;
  const float* A32 = (const float*)Av + (size_t)z * sA;
  B += (size_t)z * sB;

  // PROJ3 per-z selection (weights via sB stride; bias via bcat stride).
  void* Cz = Cv;
  const float* biasz = bias;
  bool outf16 = OUTF16;
  if (PROJ3) {
    biasz = bias + z * 1024;
    if (z == 1) Cz = C1;
    else if (z == 2) { Cz = C2; outf16 = false; }
  }

  // T1: XCD-aware bijective chunking of the (x,y) plane.
  int bx = blockIdx.x, by = blockIdx.y;
  {
    const int nwg = gridDim.x * gridDim.y;
    if ((nwg & 7) == 0) {
      int flat = by * gridDim.x + bx;
      flat = (flat & 7) * (nwg >> 3) + (flat >> 3);
      bx = flat % gridDim.x;
      by = flat / gridDim.x;
    }
  }
  const int m0 = by * 128, n0 = bx * 128;
  const int wr = (wave >> 1) * 64;
  const int wc = (wave & 1) * 64;
  const int qr = lane >> 4, lr = lane & 15;
  floatx4 acc[4][4] = {};

  // stage K-tile t (non-AF32): 4+4 = 8 global_load_lds, 16B/lane.
  auto stageAB = [&](int t, int buf) {
    const int k0 = t << 6;
#pragma unroll
    for (int it = 0; it < 4; ++it) {
      const int base = it * 256 + wave * 64;  // wave-uniform LDS dest
      const int idx = base + lane;
      const int row = idx >> 3;
      const int gs = (idx & 7) ^ (row & 7);  // inverse-swizzled global slot
      g2l16(A16 + (size_t)(m0 + row) * lda + k0 + gs * 8, &As[buf][base * 8]);
    }
#pragma unroll
    for (int it = 0; it < 4; ++it) {
      const int base = it * 256 + wave * 64;
      const int idx = base + lane;
      const int row = idx >> 3;
      const int gs = (idx & 7) ^ (row & 7);
      g2l16(B + (size_t)(n0 + row) * ldb + k0 + gs * 8, &Bs[buf][base * 8]);
    }
  };

  auto computeT = [&](int buf) {
#pragma unroll
    for (int kk = 0; kk < 64; kk += 32) {
      const int slot = (kk >> 3) + qr;  // wanted global 16B slot (0..7)
      if (INF16) {
        f16x8 af[4], bf[4];
#pragma unroll
        for (int i = 0; i < 4; ++i) {
          const int ra = wr + i * 16 + lr;
          af[i] = *(const f16x8*)&As[buf][ra * 64 + ((slot ^ (ra & 7)) * 8)];
        }
#pragma unroll
        for (int j = 0; j < 4; ++j) {
          const int rb = wc + j * 16 + lr;
          bf[j] = *(const f16x8*)&Bs[buf][rb * 64 + ((slot ^ (rb & 7)) * 8)];
        }
#pragma unroll
        for (int i = 0; i < 4; ++i)
#pragma unroll
          for (int j = 0; j < 4; ++j)
            acc[i][j] = __builtin_amdgcn_mfma_f32_16x16x32_f16(
                bf[j], af[i], acc[i][j], 0, 0, 0);
      } else {
        bf16x8 af[4], bf[4];
#pragma unroll
        for (int i = 0; i < 4; ++i) {
          const int ra = wr + i * 16 + lr;
          af[i] = *(const bf16x8*)&As[buf][ra * 64 + ((slot ^ (ra & 7)) * 8)];
        }
#pragma unroll
        for (int j = 0; j < 4; ++j) {
          const int rb = wc + j * 16 + lr;
          bf[j] = *(const bf16x8*)&Bs[buf][rb * 64 + ((slot ^ (rb & 7)) * 8)];
        }
#pragma unroll
        for (int i = 0; i < 4; ++i)
#pragma unroll
          for (int j = 0; j < 4; ++j)
            acc[i][j] = __builtin_amdgcn_mfma_f32_16x16x32_bf16(
                bf[j], af[i], acc[i][j], 0, 0, 0);
      }
    }
  };

  if (!AF32) {
    // T4 pipeline: loads for tile t+1 in flight across the barrier; only
    // counted waits (vmcnt(8)) in the main loop, vmcnt(0) only at the tail.
    const int nk = K >> 6;
    stageAB(0, 0);
    for (int t = 0; t < nk; ++t) {
      const int cur = t & 1;
      if (t + 1 < nk) {
        stageAB(t + 1, cur ^ 1);
        asm volatile("s_waitcnt vmcnt(8)" ::: "memory");  // tile t landed
      } else {
        asm volatile("s_waitcnt vmcnt(0)" ::: "memory");
      }
      __builtin_amdgcn_sched_barrier(0);
      __builtin_amdgcn_s_barrier();  // all waves' tile-t loads landed
      __builtin_amdgcn_sched_barrier(0);
      computeT(cur);
      __builtin_amdgcn_sched_barrier(0);
      __builtin_amdgcn_s_barrier();  // all waves done reading buf cur
      __builtin_amdgcn_sched_barrier(0);
    }
  } else {
    // legacy synchronous loop (ds_write staging; __syncthreads drains all)
    for (int k0 = 0; k0 < K; k0 += 64) {
      __syncthreads();
#pragma unroll
      for (int it = 0; it < 8; ++it) {
        const int idx = it * 256 + tid;  // 0..2047 float4-chunks
        const int row = idx >> 4, c4 = idx & 15;
        float4 v =
            *(const float4*)(A32 + (size_t)(m0 + row) * lda + k0 + c4 * 4);
        const int soff = (((c4 >> 1) ^ (row & 7)) * 2 + (c4 & 1)) * 4;
        *(ushort4*)&As[0][row * 64 + soff] =
            make_ushort4(f2x<INF16>(v.x), f2x<INF16>(v.y), f2x<INF16>(v.z),
                         f2x<INF16>(v.w));
      }
#pragma unroll
      for (int it = 0; it < 4; ++it) {
        const int base = it * 256 + wave * 64;
        const int idx = base + lane;
        const int row = idx >> 3;
        const int gs = (idx & 7) ^ (row & 7);
        g2l16(B + (size_t)(n0 + row) * ldb + k0 + gs * 8, &Bs[0][base * 8]);
      }
      __syncthreads();
      computeT(0);
    }
  }

  // Epilogue (operand-swapped layout):
  //   row = m0 + wr + i*16 + lr ; col = n0 + wc + j*16 + qr*4 + r
  float* Cf = (float*)Cz + (size_t)z * sC;
  unsigned short* Cb = (unsigned short*)Cz + (size_t)z * sC;
#pragma unroll
  for (int i = 0; i < 4; ++i) {
    const int row = m0 + wr + i * 16 + lr;
    float rowsum = 0.0f;
    float invl = 1.0f;
    if (MODE == 2) invl = 1.0f / lrow[(size_t)z * 2048 + row];
#pragma unroll
    for (int j = 0; j < 4; ++j) {
      const int col0 = n0 + wc + j * 16 + qr * 4;
      if (MODE == 0) {
        float4 bj = *(const float4*)(biasz + col0);
        float v0 = fmaxf(acc[i][j][0] + bj.x, 0.0f);
        float v1 = fmaxf(acc[i][j][1] + bj.y, 0.0f);
        float v2 = fmaxf(acc[i][j][2] + bj.z, 0.0f);
        float v3 = fmaxf(acc[i][j][3] + bj.w, 0.0f);
        *(ushort4*)&Cb[(size_t)row * ldc + col0] =
            make_ushort4(f2rt(v0, outf16), f2rt(v1, outf16),
                         f2rt(v2, outf16), f2rt(v3, outf16));
      } else if (MODE == 1) {
        float e0 = __expf(acc[i][j][0] - 60.0f);
        float e1 = __expf(acc[i][j][1] - 60.0f);
        float e2 = __expf(acc[i][j][2] - 60.0f);
        float e3 = __expf(acc[i][j][3] - 60.0f);
        *(ushort4*)&Cb[(size_t)row * ldc + col0] =
            make_ushort4(f2bf(e0), f2bf(e1), f2bf(e2), f2bf(e3));
        rowsum += (e0 + e1) + (e2 + e3);
      } else {
        *(float4*)&Cf[(size_t)row * ldc + col0] =
            make_float4(acc[i][j][0] * invl, acc[i][j][1] * invl,
                        acc[i][j][2] * invl, acc[i][j][3] * invl);
      }
    }
    if (MODE == 1) {
      // lanes lr, lr+16, lr+32, lr+48 hold the same row's partial sums
      rowsum += __shfl_xor(rowsum, 16);
      rowsum += __shfl_xor(rowsum, 32);
      if (lane < 16)
        atomicAdd(&lrow[(size_t)z * 2048 + row], rowsum);
    }
  }
}

// ===========================================================================
// prep: single fused dispatch replacing cvt16 + 3x wtrans + zero_f32 + bias
// concat. Block ranges:
//   [0, 8192)      : X fp32 -> Xh fp16 (2048 elems/block)
//   [8192, 8960)   : wtrans for W{q,k,v} -> Wt fp16 (256 blocks each)
//   [8960, 9024)   : zero l[16384]
//   [9024]         : bcat[3072] = {bq, bk, bv}
// ===========================================================================
__global__ __launch_bounds__(256) void prep(
    const float* __restrict__ X, unsigned short* __restrict__ Xh,
    const float* __restrict__ Wq, const float* __restrict__ Wk,
    const float* __restrict__ Wv, unsigned short* __restrict__ Wqt,
    unsigned short* __restrict__ Wkt, unsigned short* __restrict__ Wvt,
    const float* __restrict__ bq, const float* __restrict__ bk,
    const float* __restrict__ bv, float* __restrict__ bcat,
    float* __restrict__ l) {
  __shared__ unsigned short t[64][68];
  const int bid = blockIdx.x;
  const int tid = threadIdx.x;
  if (bid < 8192) {
    const int i = (bid * 256 + tid) * 8;
    float4 a = *(const float4*)(X + i);
    float4 b = *(const float4*)(X + i + 4);
    *(ushort4*)(Xh + i) = make_ushort4(f2h(a.x), f2h(a.y), f2h(a.z), f2h(a.w));
    *(ushort4*)(Xh + i + 4) =
        make_ushort4(f2h(b.x), f2h(b.y), f2h(b.z), f2h(b.w));
  } else if (bid < 8960) {
    const int w = (bid - 8192) >> 8;
    const int lb = (bid - 8192) & 255;
    const float* W = (w == 0) ? Wq : (w == 1) ? Wk : Wv;
    unsigned short* Wt = (w == 0) ? Wqt : (w == 1) ? Wkt : Wvt;
    const int n0 = (lb & 15) * 64, k0 = (lb >> 4) * 64;
#pragma unroll
    for (int it = 0; it < 4; ++it) {
      const int idx = it * 256 + tid;
      const int kr = idx >> 4, nq = idx & 15;
      float4 v = *(const float4*)&W[(size_t)(k0 + kr) * 1024 + n0 + nq * 4];
      t[kr][nq * 4 + 0] = f2h(v.x);
      t[kr][nq * 4 + 1] = f2h(v.y);
      t[kr][nq * 4 + 2] = f2h(v.z);
      t[kr][nq * 4 + 3] = f2h(v.w);
    }
    __syncthreads();
#pragma unroll
    for (int it = 0; it < 4; ++it) {
      const int idx = it * 256 + tid;
      const int nr = idx >> 4, kq = idx & 15;
      *(ushort4*)&Wt[(size_t)(n0 + nr) * 1024 + k0 + kq * 4] =
          make_ushort4(t[kq * 4 + 0][nr], t[kq * 4 + 1][nr],
                       t[kq * 4 + 2][nr], t[kq * 4 + 3][nr]);
    }
  } else if (bid < 9024) {
    const int i = (bid - 8960) * 256 + tid;
    l[i] = 0.0f;
  } else {
#pragma unroll
    for (int it = 0; it < 12; ++it) {
      const int idx = it * 256 + tid;
      bcat[idx] = (idx < 1024) ? bq[idx]
                  : (idx < 2048) ? bk[idx - 1024] : bv[idx - 2048];
    }
  }
}

// V[b][t][v] 16-bit -> Vt[b][v][t] 16-bit (dtype-agnostic)
__global__ __launch_bounds__(256) void vtrans(const unsigned short* __restrict__ V,
                                              unsigned short* __restrict__ Vt) {
  __shared__ unsigned short t[64][68];
  const int tid = threadIdx.x;
  const int v0 = blockIdx.x * 64, t0 = blockIdx.y * 64;
  const int b = blockIdx.z;
  const unsigned short* Vb = V + (size_t)b * 2048 * 1024;
  unsigned short* Vtb = Vt + (size_t)b * 1024 * 2048;
#pragma unroll
  for (int it = 0; it < 4; ++it) {
    const int idx = it * 256 + tid;
    const int tr = idx >> 4, vq = idx & 15;
    ushort4 u = *(const ushort4*)&Vb[(size_t)(t0 + tr) * 1024 + v0 + vq * 4];
    t[tr][vq * 4 + 0] = u.x;
    t[tr][vq * 4 + 1] = u.y;
    t[tr][vq * 4 + 2] = u.z;
    t[tr][vq * 4 + 3] = u.w;
  }
  __syncthreads();
#pragma unroll
  for (int it = 0; it < 4; ++it) {
    const int idx = it * 256 + tid;
    const int vr = idx >> 4, tq = idx & 15;
    *(ushort4*)&Vtb[(size_t)(v0 + vr) * 2048 + t0 + tq * 4] =
        make_ushort4(t[tq * 4 + 0][vr], t[tq * 4 + 1][vr],
                     t[tq * 4 + 2][vr], t[tq * 4 + 3][vr]);
  }
}

// Copy half-output T[b][0..1023][1024] fp32 -> out[b][roff+0..1023][1024].
__global__ __launch_bounds__(256) void copy_half(const float* __restrict__ T,
                                                 float* __restrict__ out,
                                                 int roff) {
  const size_t i = ((size_t)blockIdx.x * 256 + threadIdx.x) * 4;
  const size_t b = i >> 20;
  const size_t rem = i & 1048575;
  float4 v = *(const float4*)(T + i);
  *(float4*)(out + b * 2097152 + (size_t)roff * 1024 + rem) = v;
}

__global__ void diag_ws(float* __restrict__ out, float mb) { out[0] = mb; }

extern "C" void kernel_launch(void* const* d_in, const int* in_sizes, int n_in,
                              void* d_out, int out_size, void* d_ws, size_t ws_size,
                              hipStream_t stream) {
  const float* X = (const float*)d_in[0];
  const float* Wq = (const float*)d_in[1];
  const float* bq = (const float*)d_in[2];
  const float* Wk = (const float*)d_in[3];
  const float* bk = (const float*)d_in[4];
  const float* Wv = (const float*)d_in[5];
  const float* bv = (const float*)d_in[6];
  float* out = (float*)d_out;
  char* ws = (char*)d_ws;
  const size_t MiB = 1ull << 20;

  // ---- BIG layout (ws >= ~134 MB): E lives in ws -> no GEMM3 aliasing ----
  const size_t B_WQT = 0, B_WKT = 2 * MiB, B_WVT = 4 * MiB;
  const size_t B_Q = 6 * MiB;     // 32 MiB fp16
  const size_t B_K = 38 * MiB;    // 32 MiB fp16
  const size_t B_E = 70 * MiB;    // 64 MiB bf16
  const size_t B_L = 134 * MiB;   // 64 KiB l + 16 KiB bcat
  const size_t NEEDED_BIG = B_L + 65536 + 16384;

  // ---- SMALL layout: E overlays d_out, bounce GEMM3 ----
  const size_t S_WQT = 0, S_WKT = 2 * MiB, S_WVT = 4 * MiB;
  const size_t S_Q = 6 * MiB, S_K = 38 * MiB, S_L = 70 * MiB;
  const size_t NEEDED_SMALL = S_L + 65536 + 16384;

  if (ws_size >= NEEDED_BIG) {
    unsigned short* Wqt = (unsigned short*)(ws + B_WQT);
    unsigned short* Wkt = (unsigned short*)(ws + B_WKT);
    unsigned short* Wvt = (unsigned short*)(ws + B_WVT);
    unsigned short* Q   = (unsigned short*)(ws + B_Q);
    unsigned short* Kb  = (unsigned short*)(ws + B_K);
    unsigned short* E   = (unsigned short*)(ws + B_E);
    float* l            = (float*)(ws + B_L);
    float* bcat         = (float*)(ws + B_L + 65536);
    unsigned short* Xh = (unsigned short*)d_out;
    unsigned short* V  = (unsigned short*)d_out + 16384ull * 1024;

    prep<<<9025, 256, 0, stream>>>(X, Xh, Wq, Wk, Wv, Wqt, Wkt, Wvt,
                                   bq, bk, bv, bcat, l);

    // fused Q/K/V projections: z selects weight (sB stride), bias (bcat),
    // output pointer; Q,K fp16 -> ws; V bf16 -> d_out upper half.
    gemm_bt<0, false, true, true, true><<<dim3(8, 128, 3), 256, 0, stream>>>(
        Xh, 1024, 0, Wqt, 1024, 1048576, Q, 1024, 0, 1024, bcat, nullptr,
        Kb, V);

    // E[b] = exp(Q K^T - 60) bf16 into ws; l rowsums
    gemm_bt<1, false, true, false, false><<<dim3(16, 16, 8), 256, 0, stream>>>(
        Q, 1024, 2048L * 1024, Kb, 1024, 2048L * 1024,
        E, 2048, 2048L * 2048, 1024, nullptr, l, nullptr, nullptr);

    // V -> V^T into Q's space (Q dead after GEMM2)
    vtrans<<<dim3(16, 32, 8), 256, 0, stream>>>(V, Q);

    // out = (E * Vt^T)/l straight into d_out
    gemm_bt<2, false, false, false, false><<<dim3(8, 16, 8), 256, 0, stream>>>(
        E, 2048, 2048L * 2048, Q, 2048, 1024L * 2048,
        out, 1024, 2048L * 1024, 2048, nullptr, l, nullptr, nullptr);
    return;
  }

  if (ws_size < NEEDED_SMALL) {
    diag_ws<<<1, 1, 0, stream>>>(out, (float)(ws_size >> 20));
    return;
  }

  // ---------------- SMALL path ----------------
  unsigned short* Wqt = (unsigned short*)(ws + S_WQT);
  unsigned short* Wkt = (unsigned short*)(ws + S_WKT);
  unsigned short* Wvt = (unsigned short*)(ws + S_WVT);
  unsigned short* Q   = (unsigned short*)(ws + S_Q);
  unsigned short* Kb  = (unsigned short*)(ws + S_K);
  float* l            = (float*)(ws + S_L);
  float* bcat         = (float*)(ws + S_L + 65536);
  unsigned short* Xh = (unsigned short*)d_out;
  unsigned short* E  = (unsigned short*)d_out;

  prep<<<9025, 256, 0, stream>>>(X, Xh, Wq, Wk, Wv, Wqt, Wkt, Wvt,
                                 bq, bk, bv, bcat, l);

  // fused Q/K projections (z=2); V comes later from fp32 X (E overlays Xh)
  gemm_bt<0, false, true, true, true><<<dim3(8, 128, 2), 256, 0, stream>>>(
      Xh, 1024, 0, Wqt, 1024, 1048576, Q, 1024, 0, 1024, bcat, nullptr,
      Kb, nullptr);

  gemm_bt<1, false, true, false, false><<<dim3(16, 16, 8), 256, 0, stream>>>(
      Q, 1024, 2048L * 1024, Kb, 1024, 2048L * 1024,
      E, 2048, 2048L * 2048, 1024, nullptr, l, nullptr, nullptr);

  // V-proj from fp32 X (E overlays Xh in d_out): legacy AF32 path
  gemm_bt<0, true, true, false, false><<<dim3(8, 128, 1), 256, 0, stream>>>(
      X, 1024, 0, Wvt, 1024, 0, Kb, 1024, 0, 1024, bv, nullptr,
      nullptr, nullptr);

  vtrans<<<dim3(16, 32, 8), 256, 0, stream>>>(Kb, Q);

  float* T = (float*)Kb;
  gemm_bt<2, false, false, false, false><<<dim3(8, 8, 8), 256, 0, stream>>>(
      E, 2048, 2048L * 2048, Q, 2048, 1024L * 2048,
      T, 1024, 1024L * 1024, 2048, nullptr, l, nullptr, nullptr);
  copy_half<<<8192, 256, 0, stream>>>(T, out, 0);
  gemm_bt<2, false, false, false, false><<<dim3(8, 8, 8), 256, 0, stream>>>(
      E + 1024L * 2048, 2048, 2048L * 2048, Q, 2048, 1024L * 2048,
      T, 1024, 1024L * 1024, 2048, nullptr, l + 1024, nullptr, nullptr);
  copy_half<<<8192, 256, 0, stream>>>(T, out, 1024);
}